// Round 19
// baseline (553.798 us; speedup 1.0000x reference)
//
#include <hip/hip_runtime.h>

#define NN 12800
#define NE 204800
#define BCAP 64   // bucket capacity per node; P(deg>64) ~ 1e-18
#define PBLK 256  // persistent grid: 256 blocks x 1024 thr (launched OK in R5)

// packed-weight layout (floats) -- shared by g_wpack and s_pack
#define OFF_W2 0        // [j*276 + kp*16 + d], bias at [j*276+256+kp]  (4416)
#define OFF_CR 4416     // [k*20+d] = cr[d*16+k]                        (320)
#define OFF_WI 4736     // [row*20+d]                                   (960)
#define OFF_WH 5696     // [row*20+d]                                   (960)
#define OFF_CB 6656     // (16)
#define OFF_BI 6672     // (48)
#define OFF_BH 6720     // (48)
#define PACKN  6768     // total floats (27072 B)

// ---------------- static device scratch (~57 MB) ----------------
__device__ __align__(16) float g_outA[NN * 16];        // node features ping
__device__ __align__(16) float g_outB[NN * 16];        // node features pong
__device__ __align__(16) float g_ehsB[NN * BCAP * 16]; // eh buckets, dst-grouped (fp32)
__device__ __align__(16) int g_srcB[NN * BCAP];        // src per bucket slot
__device__ int g_cnt[NN];                              // in-degree / cursor (reset by last round)
__device__ __align__(16) float g_wpack[PACKN];         // pre-transposed weights

// ---- custom grid barrier (sense-reversing; correctness proven in R5) ----
__device__ int g_bar_cnt   = 0;
__device__ int g_bar_sense = 0;

__device__ __forceinline__ void gbar(int* sense) {
    __syncthreads();
    if (threadIdx.x == 0) {
        int s = *sense ^ 1;
        *sense = s;
        __threadfence();  // release
        int a = __hip_atomic_fetch_add(&g_bar_cnt, 1, __ATOMIC_ACQ_REL,
                                       __HIP_MEMORY_SCOPE_AGENT);
        if (a == PBLK - 1) {
            __hip_atomic_store(&g_bar_cnt, 0, __ATOMIC_RELAXED,
                               __HIP_MEMORY_SCOPE_AGENT);
            __hip_atomic_store(&g_bar_sense, s, __ATOMIC_RELEASE,
                               __HIP_MEMORY_SCOPE_AGENT);
        } else {
            while (__hip_atomic_load(&g_bar_sense, __ATOMIC_ACQUIRE,
                                     __HIP_MEMORY_SCOPE_AGENT) != s)
                __builtin_amdgcn_s_sleep(16);
        }
        __threadfence();  // acquire
    }
    __syncthreads();
}

// ---- S0: lin0 + eh/bucket scatter (edge-parallel); block 0 builds wpack ----
__global__ __launch_bounds__(256) void k_setup(const int* __restrict__ ei,
                                               const float* __restrict__ x,
                                               const float* __restrict__ lw,
                                               const float* __restrict__ lb,
                                               const float* __restrict__ attr,
                                               const float* __restrict__ w1,
                                               const float* __restrict__ b1,
                                               const float* __restrict__ nn2_w,
                                               const float* __restrict__ nn2_b,
                                               const float* __restrict__ cr,
                                               const float* __restrict__ cb,
                                               const float* __restrict__ wi,
                                               const float* __restrict__ wh,
                                               const float* __restrict__ bi,
                                               const float* __restrict__ bh) {
    int gid = blockIdx.x * 256 + threadIdx.x;

    if (blockIdx.x == 0) {
        int tt = threadIdx.x;
        for (int i = tt; i < 4096; i += 256)
            g_wpack[OFF_W2 + (i & 15) * 276 + ((i >> 4) & 15) * 16 + (i >> 8)] = nn2_w[i];
        g_wpack[OFF_W2 + (tt >> 4) * 276 + 256 + (tt & 15)] = nn2_b[tt];
        g_wpack[OFF_CR + (tt & 15) * 20 + (tt >> 4)] = cr[tt];
        for (int i = tt; i < 768; i += 256) {
            g_wpack[OFF_WI + (i >> 4) * 20 + (i & 15)] = wi[i];
            g_wpack[OFF_WH + (i >> 4) * 20 + (i & 15)] = wh[i];
        }
        if (tt < 16) g_wpack[OFF_CB + tt] = cb[tt];
        if (tt < 48) { g_wpack[OFF_BI + tt] = bi[tt]; g_wpack[OFF_BH + tt] = bh[tt]; }
    }

    if (gid < NN) {
        int n = gid;
        float x0 = x[n * 3 + 0], x1 = x[n * 3 + 1], x2 = x[n * 3 + 2];
        float v[16];
#pragma unroll
        for (int j = 0; j < 16; ++j) {
            float t = lb[j] + x0 * lw[j * 3 + 0] + x1 * lw[j * 3 + 1] + x2 * lw[j * 3 + 2];
            v[j] = fmaxf(t, 0.0f);
        }
#pragma unroll
        for (int j = 0; j < 16; j += 4)
            *(float4*)(g_outA + n * 16 + j) = make_float4(v[j], v[j + 1], v[j + 2], v[j + 3]);
    }

    int e = gid;
    int s = ei[e], d = ei[NE + e];
    float4 a = *(const float4*)(attr + e * 4);
    float v[16];
#pragma unroll
    for (int j = 0; j < 16; ++j) {
        float t = b1[j] + a.x * w1[j * 4 + 0] + a.y * w1[j * 4 + 1] +
                  a.z * w1[j * 4 + 2] + a.w * w1[j * 4 + 3];
        v[j] = fmaxf(t, 0.0f);
    }
    int pos = atomicAdd(&g_cnt[d], 1);
    if (pos < BCAP) {
        int slot = d * BCAP + pos;
        g_srcB[slot] = s;
#pragma unroll
        for (int j = 0; j < 16; j += 4)
            *(float4*)(g_ehsB + slot * 16 + j) = make_float4(v[j], v[j + 1], v[j + 2], v[j + 3]);
    }
}

// ---- the R16 round body, shared by persistent and fallback kernels ----
__device__ __forceinline__ void round_body(const float* s_pack, int n, int j,
                                           const float* cur, float* nxt,
                                           float* out_final, int last) {
    const float* s_W2  = s_pack + OFF_W2;
    const float* s_crT = s_pack + OFF_CR;
    const float* s_wi  = s_pack + OFF_WI;
    const float* s_wh  = s_pack + OFF_WH;
    const float* s_cb  = s_pack + OFF_CB;
    const float* s_bi  = s_pack + OFF_BI;
    const float* s_bh  = s_pack + OFF_BH;

    int deg = min(g_cnt[n], BCAP);               // clamp guards replay corruption
    if (last && j == 0) g_cnt[n] = 0;            // reset for next call's k_setup
    const int base = n * BCAP;

    float Gd[16];
#pragma unroll
    for (int d = 0; d < 16; ++d) Gd[d] = 0.0f;
    float r16 = 0.0f;
#pragma unroll 4
    for (int q = 0; q < deg; ++q) {
        int slot = base + q;
        int s = min(g_srcB[slot], NN - 1);       // group-uniform
        const float* orow = cur + s * 16;
        float ej = g_ehsB[slot * 16 + j];        // coalesced 64B per group
        float4 o0 = *(const float4*)(orow + 0);  // broadcast
        float4 o1 = *(const float4*)(orow + 4);
        float4 o2 = *(const float4*)(orow + 8);
        float4 o3 = *(const float4*)(orow + 12);
        Gd[0]  += ej * o0.x; Gd[1]  += ej * o0.y; Gd[2]  += ej * o0.z; Gd[3]  += ej * o0.w;
        Gd[4]  += ej * o1.x; Gd[5]  += ej * o1.y; Gd[6]  += ej * o1.z; Gd[7]  += ej * o1.w;
        Gd[8]  += ej * o2.x; Gd[9]  += ej * o2.y; Gd[10] += ej * o2.z; Gd[11] += ej * o2.w;
        Gd[12] += ej * o3.x; Gd[13] += ej * o3.y; Gd[14] += ej * o3.z; Gd[15] += ej * o3.w;
        r16 += orow[j];
    }

    const float* wj = s_W2 + j * 276;
    float part[16];
#pragma unroll
    for (int kp = 0; kp < 16; ++kp) {
        const float* w = wj + kp * 16;
        float4 w0 = *(const float4*)(w + 0);
        float4 w1 = *(const float4*)(w + 4);
        float4 w2 = *(const float4*)(w + 8);
        float4 w3 = *(const float4*)(w + 12);
        part[kp] = Gd[0] * w0.x + Gd[1] * w0.y + Gd[2] * w0.z + Gd[3] * w0.w
                 + Gd[4] * w1.x + Gd[5] * w1.y + Gd[6] * w1.z + Gd[7] * w1.w
                 + Gd[8] * w2.x + Gd[9] * w2.y + Gd[10] * w2.z + Gd[11] * w2.w
                 + Gd[12] * w3.x + Gd[13] * w3.y + Gd[14] * w3.z + Gd[15] * w3.w;
    }
    {
        float4 b0 = *(const float4*)(wj + 256);
        float4 b1 = *(const float4*)(wj + 260);
        float4 b2v = *(const float4*)(wj + 264);
        float4 b3 = *(const float4*)(wj + 268);
        part[0] += r16 * b0.x;  part[1] += r16 * b0.y;  part[2] += r16 * b0.z;  part[3] += r16 * b0.w;
        part[4] += r16 * b1.x;  part[5] += r16 * b1.y;  part[6] += r16 * b1.z;  part[7] += r16 * b1.w;
        part[8] += r16 * b2v.x; part[9] += r16 * b2v.y; part[10] += r16 * b2v.z; part[11] += r16 * b2v.w;
        part[12] += r16 * b3.x; part[13] += r16 * b3.y; part[14] += r16 * b3.z; part[15] += r16 * b3.w;
    }

    float w8[8];
#pragma unroll
    for (int i = 0; i < 8; ++i) {
        int keep = 2 * i + (j & 1);
        w8[i] = part[keep] + __shfl_xor(part[keep ^ 1], 1);
    }
    float w4[4];
#pragma unroll
    for (int i = 0; i < 4; ++i) {
        int keep = 2 * i + ((j >> 1) & 1);
        w4[i] = w8[keep] + __shfl_xor(w8[keep ^ 1], 2);
    }
    float w2[2];
#pragma unroll
    for (int i = 0; i < 2; ++i) {
        int keep = 2 * i + ((j >> 2) & 1);
        w2[i] = w4[keep] + __shfl_xor(w4[keep ^ 1], 4);
    }
    float aggr;
    {
        int keep = (j >> 3) & 1;
        aggr = w2[keep] + __shfl_xor(w2[keep ^ 1], 8);
    }
    float invd = 1.0f / (float)(deg > 0 ? deg : 1);
    float a_k = aggr * invd;
    const int k = j;

    const float* nrow = cur + n * 16;
    float4 q0 = *(const float4*)(nrow + 0);
    float4 q1 = *(const float4*)(nrow + 4);
    float4 q2 = *(const float4*)(nrow + 8);
    float4 q3 = *(const float4*)(nrow + 12);
    float o[16] = {q0.x, q0.y, q0.z, q0.w, q1.x, q1.y, q1.z, q1.w,
                   q2.x, q2.y, q2.z, q2.w, q3.x, q3.y, q3.z, q3.w};
    float ok = o[k];

    float mcc = s_cb[k] + a_k;
    {
        const float* c = s_crT + k * 20;
        float4 c0 = *(const float4*)(c + 0);
        float4 c1 = *(const float4*)(c + 4);
        float4 c2 = *(const float4*)(c + 8);
        float4 c3 = *(const float4*)(c + 12);
        mcc += o[0] * c0.x + o[1] * c0.y + o[2] * c0.z + o[3] * c0.w
             + o[4] * c1.x + o[5] * c1.y + o[6] * c1.z + o[7] * c1.w
             + o[8] * c2.x + o[9] * c2.y + o[10] * c2.z + o[11] * c2.w
             + o[12] * c3.x + o[13] * c3.y + o[14] * c3.z + o[15] * c3.w;
    }
    float m = fmaxf(mcc, 0.0f);

    float md[16];
#pragma unroll
    for (int d = 0; d < 16; ++d) md[d] = __shfl(m, d, 16);

    float ir = s_bi[k], iz = s_bi[16 + k], in_ = s_bi[32 + k];
    float hr = s_bh[k], hz = s_bh[16 + k], hh = s_bh[32 + k];
#pragma unroll
    for (int g = 0; g < 3; ++g) {
        const float* wrow_i = s_wi + (g * 16 + k) * 20;
        const float* wrow_h = s_wh + (g * 16 + k) * 20;
        float acc_i = 0.0f, acc_h = 0.0f;
#pragma unroll
        for (int d4 = 0; d4 < 4; ++d4) {
            float4 wiv = *(const float4*)(wrow_i + d4 * 4);
            float4 whv = *(const float4*)(wrow_h + d4 * 4);
            acc_i += md[d4 * 4] * wiv.x + md[d4 * 4 + 1] * wiv.y
                   + md[d4 * 4 + 2] * wiv.z + md[d4 * 4 + 3] * wiv.w;
            acc_h += o[d4 * 4] * whv.x + o[d4 * 4 + 1] * whv.y
                   + o[d4 * 4 + 2] * whv.z + o[d4 * 4 + 3] * whv.w;
        }
        if (g == 0) { ir += acc_i; hr += acc_h; }
        else if (g == 1) { iz += acc_i; hz += acc_h; }
        else { in_ += acc_i; hh += acc_h; }
    }
    float rg = 1.0f / (1.0f + __expf(-(ir + hr)));
    float z  = 1.0f / (1.0f + __expf(-(iz + hz)));
    float nh = tanhf(in_ + rg * hh);
    float hnew = (1.0f - z) * nh + z * ok;

    if (last) out_final[n * 16 + k] = hnew;
    else      nxt[n * 16 + k] = hnew;
}

// ---- persistent: all 6 rounds, 1 dispatch. 256 blocks x 1024 thr. ----
__global__ __launch_bounds__(1024) void k_persist(float* __restrict__ out_final) {
    __shared__ __align__(16) float s_pack[PACKN];
    int t = threadIdx.x;
    {   // stage weights ONCE for all 6 rounds
        const float4* srcp = (const float4*)g_wpack;
        float4* dstp = (float4*)s_pack;
        for (int idx = t; idx < PACKN / 4; idx += 1024) dstp[idx] = srcp[idx];
    }
    __syncthreads();

    int sense = 0;
    const int g = blockIdx.x * 64 + (t >> 4);    // global 16-lane group id (16384)
    const int j = t & 15;

    for (int r = 0; r < 6; ++r) {
        const float* cur = (r & 1) ? g_outB : g_outA;
        float*       nxt = (r & 1) ? g_outA : g_outB;
        if (g < NN)
            round_body(s_pack, g, j, cur, nxt, out_final, r == 5 ? 1 : 0);
        gbar(&sense);                            // 6 barriers: even parity
    }
}

// ---- fallback: R16's per-round dispatch ----
__global__ __launch_bounds__(256) void k_round(float* __restrict__ out_final,
                                               int flip, int last) {
    __shared__ __align__(16) float s_pack[PACKN];
    int t = threadIdx.x;
    {
        const float4* srcp = (const float4*)g_wpack;
        float4* dstp = (float4*)s_pack;
#pragma unroll
        for (int i = 0; i < PACKN / 4 / 256 + 1; ++i) {
            int idx = t + i * 256;
            if (idx < PACKN / 4) dstp[idx] = srcp[idx];
        }
    }
    __syncthreads();
    const float* cur = flip ? g_outB : g_outA;
    float*       nxt = flip ? g_outA : g_outB;
    int n = blockIdx.x * 16 + (t >> 4);
    round_body(s_pack, n, t & 15, cur, nxt, out_final, last);
}

extern "C" void kernel_launch(void* const* d_in, const int* in_sizes, int n_in,
                              void* d_out, int out_size, void* d_ws, size_t ws_size,
                              hipStream_t stream) {
    const float* x         = (const float*)d_in[0];
    const int*   ei        = (const int*)d_in[1];
    const float* edge_attr = (const float*)d_in[2];
    const float* lin0_w    = (const float*)d_in[3];
    const float* lin0_b    = (const float*)d_in[4];
    const float* nn1_w     = (const float*)d_in[5];
    const float* nn1_b     = (const float*)d_in[6];
    const float* nn2_w     = (const float*)d_in[7];
    const float* nn2_b     = (const float*)d_in[8];
    const float* conv_root = (const float*)d_in[9];
    const float* conv_bias = (const float*)d_in[10];
    const float* gru_w_ih  = (const float*)d_in[11];
    const float* gru_w_hh  = (const float*)d_in[12];
    const float* gru_b_ih  = (const float*)d_in[13];
    const float* gru_b_hh  = (const float*)d_in[14];
    float* out = (float*)d_out;

    k_setup<<<NE / 256, 256, 0, stream>>>(ei, x, lin0_w, lin0_b, edge_attr,
                                          nn1_w, nn1_b, nn2_w, nn2_b, conv_root,
                                          conv_bias, gru_w_ih, gru_w_hh,
                                          gru_b_ih, gru_b_hh);

    void* args[] = { (void*)&out };
    hipError_t err = hipLaunchCooperativeKernel((const void*)k_persist,
                                                dim3(PBLK), dim3(1024),
                                                args, 0, stream);
    if (err != hipSuccess) {
        for (int r = 0; r < 6; ++r)
            k_round<<<NN / 16, 256, 0, stream>>>(out, r & 1, r == 5 ? 1 : 0);
    }
}

// Round 20
// 236.068 us; speedup vs baseline: 2.3459x; 2.3459x over previous
//
#include <hip/hip_runtime.h>

#define NN 12800
#define NE 204800
#define BCAP 64   // bucket capacity per node; P(deg>64) ~ 1e-18
#define NPB 50    // nodes per round-block; 256 blocks x 50 = 12800 = NN
#define RTHR (NPB * 16)  // 800 threads per round-block -> 1 block per CU

// packed-weight layout (floats) -- shared by g_wpack and s_pack
#define OFF_W2 0        // [j*276 + kp*16 + d], bias at [j*276+256+kp]  (4416)
#define OFF_CR 4416     // [k*20+d] = cr[d*16+k]                        (320)
#define OFF_WI 4736     // [row*20+d]                                   (960)
#define OFF_WH 5696     // [row*20+d]                                   (960)
#define OFF_CB 6656     // (16)
#define OFF_BI 6672     // (48)
#define OFF_BH 6720     // (48)
#define PACKN  6768     // total floats (27072 B)

// ---------------- static device scratch (~57 MB) ----------------
__device__ __align__(16) float g_outA[NN * 16];        // node features ping
__device__ __align__(16) float g_outB[NN * 16];        // node features pong
__device__ __align__(16) float g_ehsB[NN * BCAP * 16]; // eh buckets, dst-grouped
__device__ __align__(16) int g_srcB[NN * BCAP];        // src per bucket slot
__device__ int g_cnt[NN];                              // in-degree / cursor (reset by last round)
__device__ __align__(16) float g_wpack[PACKN];         // pre-transposed weights

// ---- S0: lin0 + eh/bucket scatter (edge-parallel); block 0 builds wpack ----
__global__ __launch_bounds__(256) void k_setup(const int* __restrict__ ei,
                                               const float* __restrict__ x,
                                               const float* __restrict__ lw,
                                               const float* __restrict__ lb,
                                               const float* __restrict__ attr,
                                               const float* __restrict__ w1,
                                               const float* __restrict__ b1,
                                               const float* __restrict__ nn2_w,
                                               const float* __restrict__ nn2_b,
                                               const float* __restrict__ cr,
                                               const float* __restrict__ cb,
                                               const float* __restrict__ wi,
                                               const float* __restrict__ wh,
                                               const float* __restrict__ bi,
                                               const float* __restrict__ bh) {
    int gid = blockIdx.x * 256 + threadIdx.x;

    if (blockIdx.x == 0) {
        int tt = threadIdx.x;
        for (int i = tt; i < 4096; i += 256)
            g_wpack[OFF_W2 + (i & 15) * 276 + ((i >> 4) & 15) * 16 + (i >> 8)] = nn2_w[i];
        g_wpack[OFF_W2 + (tt >> 4) * 276 + 256 + (tt & 15)] = nn2_b[tt];
        g_wpack[OFF_CR + (tt & 15) * 20 + (tt >> 4)] = cr[tt];
        for (int i = tt; i < 768; i += 256) {
            g_wpack[OFF_WI + (i >> 4) * 20 + (i & 15)] = wi[i];
            g_wpack[OFF_WH + (i >> 4) * 20 + (i & 15)] = wh[i];
        }
        if (tt < 16) g_wpack[OFF_CB + tt] = cb[tt];
        if (tt < 48) { g_wpack[OFF_BI + tt] = bi[tt]; g_wpack[OFF_BH + tt] = bh[tt]; }
    }

    if (gid < NN) {
        int n = gid;
        float x0 = x[n * 3 + 0], x1 = x[n * 3 + 1], x2 = x[n * 3 + 2];
        float v[16];
#pragma unroll
        for (int j = 0; j < 16; ++j) {
            float t = lb[j] + x0 * lw[j * 3 + 0] + x1 * lw[j * 3 + 1] + x2 * lw[j * 3 + 2];
            v[j] = fmaxf(t, 0.0f);
        }
#pragma unroll
        for (int j = 0; j < 16; j += 4)
            *(float4*)(g_outA + n * 16 + j) = make_float4(v[j], v[j + 1], v[j + 2], v[j + 3]);
    }

    int e = gid;
    int s = ei[e], d = ei[NE + e];
    float4 a = *(const float4*)(attr + e * 4);
    float v[16];
#pragma unroll
    for (int j = 0; j < 16; ++j) {
        float t = b1[j] + a.x * w1[j * 4 + 0] + a.y * w1[j * 4 + 1] +
                  a.z * w1[j * 4 + 2] + a.w * w1[j * 4 + 3];
        v[j] = fmaxf(t, 0.0f);
    }
    int pos = atomicAdd(&g_cnt[d], 1);
    if (pos < BCAP) {
        int slot = d * BCAP + pos;
        g_srcB[slot] = s;
#pragma unroll
        for (int j = 0; j < 16; j += 4)
            *(float4*)(g_ehsB + slot * 16 + j) = make_float4(v[j], v[j + 1], v[j + 2], v[j + 3]);
    }
}

// ---- one round. 256 blocks x 800 thr = 50 nodes x 16 lanes; 1 block/CU. ----
__global__ __launch_bounds__(RTHR) void k_round(float* __restrict__ out_final,
                                                int flip, int last) {
    __shared__ __align__(16) float s_pack[PACKN];
    int t = threadIdx.x;
    {   // straight coalesced float4 copy of the pre-transposed pack
        const float4* srcp = (const float4*)g_wpack;
        float4* dstp = (float4*)s_pack;
        for (int idx = t; idx < PACKN / 4; idx += RTHR) dstp[idx] = srcp[idx];
    }
    __syncthreads();

    const float* s_W2  = s_pack + OFF_W2;
    const float* s_crT = s_pack + OFF_CR;
    const float* s_wi  = s_pack + OFF_WI;
    const float* s_wh  = s_pack + OFF_WH;
    const float* s_cb  = s_pack + OFF_CB;
    const float* s_bi  = s_pack + OFF_BI;
    const float* s_bh  = s_pack + OFF_BH;

    const float* cur = flip ? g_outB : g_outA;
    float*       nxt = flip ? g_outA : g_outB;

    const int grp = t >> 4, j = t & 15;          // lane j inside group (grp < 50)
    const int n = blockIdx.x * NPB + grp;
    int deg = min(g_cnt[n], BCAP);               // clamp guards replay corruption
    if (last && j == 0) g_cnt[n] = 0;            // reset for next call's k_setup
    const int base = n * BCAP;

    // ---- G-row accumulation (registers, zero LDS) ----
    float Gd[16];
#pragma unroll
    for (int d = 0; d < 16; ++d) Gd[d] = 0.0f;
    float r16 = 0.0f;
#pragma unroll 4
    for (int q = 0; q < deg; ++q) {
        int slot = base + q;
        int s = min(g_srcB[slot], NN - 1);       // group-uniform
        const float* orow = cur + s * 16;
        float ej = g_ehsB[slot * 16 + j];        // coalesced 64B per group
        float4 o0 = *(const float4*)(orow + 0);  // broadcast
        float4 o1 = *(const float4*)(orow + 4);
        float4 o2 = *(const float4*)(orow + 8);
        float4 o3 = *(const float4*)(orow + 12);
        Gd[0]  += ej * o0.x; Gd[1]  += ej * o0.y; Gd[2]  += ej * o0.z; Gd[3]  += ej * o0.w;
        Gd[4]  += ej * o1.x; Gd[5]  += ej * o1.y; Gd[6]  += ej * o1.z; Gd[7]  += ej * o1.w;
        Gd[8]  += ej * o2.x; Gd[9]  += ej * o2.y; Gd[10] += ej * o2.z; Gd[11] += ej * o2.w;
        Gd[12] += ej * o3.x; Gd[13] += ej * o3.y; Gd[14] += ej * o3.z; Gd[15] += ej * o3.w;
        r16 += orow[j];
    }

    // ---- contraction: part[k'] via b128 s_W2 reads ----
    const float* wj = s_W2 + j * 276;
    float part[16];
#pragma unroll
    for (int kp = 0; kp < 16; ++kp) {
        const float* w = wj + kp * 16;
        float4 w0 = *(const float4*)(w + 0);
        float4 w1 = *(const float4*)(w + 4);
        float4 w2 = *(const float4*)(w + 8);
        float4 w3 = *(const float4*)(w + 12);
        part[kp] = Gd[0] * w0.x + Gd[1] * w0.y + Gd[2] * w0.z + Gd[3] * w0.w
                 + Gd[4] * w1.x + Gd[5] * w1.y + Gd[6] * w1.z + Gd[7] * w1.w
                 + Gd[8] * w2.x + Gd[9] * w2.y + Gd[10] * w2.z + Gd[11] * w2.w
                 + Gd[12] * w3.x + Gd[13] * w3.y + Gd[14] * w3.z + Gd[15] * w3.w;
    }
    {   // fold bias row: part[k'] += r16 * b2[j*16+k']
        float4 b0 = *(const float4*)(wj + 256);
        float4 b1 = *(const float4*)(wj + 260);
        float4 b2v = *(const float4*)(wj + 264);
        float4 b3 = *(const float4*)(wj + 268);
        part[0] += r16 * b0.x;  part[1] += r16 * b0.y;  part[2] += r16 * b0.z;  part[3] += r16 * b0.w;
        part[4] += r16 * b1.x;  part[5] += r16 * b1.y;  part[6] += r16 * b1.z;  part[7] += r16 * b1.w;
        part[8] += r16 * b2v.x; part[9] += r16 * b2v.y; part[10] += r16 * b2v.z; part[11] += r16 * b2v.w;
        part[12] += r16 * b3.x; part[13] += r16 * b3.y; part[14] += r16 * b3.z; part[15] += r16 * b3.w;
    }

    // ---- j-reduction: halving butterfly, 15 shfl_xor; lane j ends with a[j] --
    float w8[8];
#pragma unroll
    for (int i = 0; i < 8; ++i) {
        int keep = 2 * i + (j & 1);
        w8[i] = part[keep] + __shfl_xor(part[keep ^ 1], 1);
    }
    float w4[4];
#pragma unroll
    for (int i = 0; i < 4; ++i) {
        int keep = 2 * i + ((j >> 1) & 1);
        w4[i] = w8[keep] + __shfl_xor(w8[keep ^ 1], 2);
    }
    float w2[2];
#pragma unroll
    for (int i = 0; i < 2; ++i) {
        int keep = 2 * i + ((j >> 2) & 1);
        w2[i] = w4[keep] + __shfl_xor(w4[keep ^ 1], 4);
    }
    float aggr;
    {
        int keep = (j >> 3) & 1;
        aggr = w2[keep] + __shfl_xor(w2[keep ^ 1], 8);
    }
    float invd = 1.0f / (float)(deg > 0 ? deg : 1);
    float a_k = aggr * invd;
    const int k = j;

    // ---- node update: conv + GRU (b128 LDS weights) ----
    const float* nrow = cur + n * 16;
    float4 q0 = *(const float4*)(nrow + 0);
    float4 q1 = *(const float4*)(nrow + 4);
    float4 q2 = *(const float4*)(nrow + 8);
    float4 q3 = *(const float4*)(nrow + 12);
    float o[16] = {q0.x, q0.y, q0.z, q0.w, q1.x, q1.y, q1.z, q1.w,
                   q2.x, q2.y, q2.z, q2.w, q3.x, q3.y, q3.z, q3.w};
    float ok = o[k];

    float mcc = s_cb[k] + a_k;
    {
        const float* c = s_crT + k * 20;
        float4 c0 = *(const float4*)(c + 0);
        float4 c1 = *(const float4*)(c + 4);
        float4 c2 = *(const float4*)(c + 8);
        float4 c3 = *(const float4*)(c + 12);
        mcc += o[0] * c0.x + o[1] * c0.y + o[2] * c0.z + o[3] * c0.w
             + o[4] * c1.x + o[5] * c1.y + o[6] * c1.z + o[7] * c1.w
             + o[8] * c2.x + o[9] * c2.y + o[10] * c2.z + o[11] * c2.w
             + o[12] * c3.x + o[13] * c3.y + o[14] * c3.z + o[15] * c3.w;
    }
    float m = fmaxf(mcc, 0.0f);

    float md[16];
#pragma unroll
    for (int d = 0; d < 16; ++d) md[d] = __shfl(m, d, 16);

    float ir = s_bi[k], iz = s_bi[16 + k], in_ = s_bi[32 + k];
    float hr = s_bh[k], hz = s_bh[16 + k], hh = s_bh[32 + k];
#pragma unroll
    for (int g = 0; g < 3; ++g) {
        const float* wrow_i = s_wi + (g * 16 + k) * 20;
        const float* wrow_h = s_wh + (g * 16 + k) * 20;
        float acc_i = 0.0f, acc_h = 0.0f;
#pragma unroll
        for (int d4 = 0; d4 < 4; ++d4) {
            float4 wiv = *(const float4*)(wrow_i + d4 * 4);
            float4 whv = *(const float4*)(wrow_h + d4 * 4);
            acc_i += md[d4 * 4] * wiv.x + md[d4 * 4 + 1] * wiv.y
                   + md[d4 * 4 + 2] * wiv.z + md[d4 * 4 + 3] * wiv.w;
            acc_h += o[d4 * 4] * whv.x + o[d4 * 4 + 1] * whv.y
                   + o[d4 * 4 + 2] * whv.z + o[d4 * 4 + 3] * whv.w;
        }
        if (g == 0) { ir += acc_i; hr += acc_h; }
        else if (g == 1) { iz += acc_i; hz += acc_h; }
        else { in_ += acc_i; hh += acc_h; }
    }
    float rg = 1.0f / (1.0f + __expf(-(ir + hr)));
    float z  = 1.0f / (1.0f + __expf(-(iz + hz)));
    float nh = tanhf(in_ + rg * hh);
    float hnew = (1.0f - z) * nh + z * ok;

    if (last) out_final[n * 16 + k] = hnew;
    else      nxt[n * 16 + k] = hnew;
}

extern "C" void kernel_launch(void* const* d_in, const int* in_sizes, int n_in,
                              void* d_out, int out_size, void* d_ws, size_t ws_size,
                              hipStream_t stream) {
    const float* x         = (const float*)d_in[0];
    const int*   ei        = (const int*)d_in[1];
    const float* edge_attr = (const float*)d_in[2];
    const float* lin0_w    = (const float*)d_in[3];
    const float* lin0_b    = (const float*)d_in[4];
    const float* nn1_w     = (const float*)d_in[5];
    const float* nn1_b     = (const float*)d_in[6];
    const float* nn2_w     = (const float*)d_in[7];
    const float* nn2_b     = (const float*)d_in[8];
    const float* conv_root = (const float*)d_in[9];
    const float* conv_bias = (const float*)d_in[10];
    const float* gru_w_ih  = (const float*)d_in[11];
    const float* gru_w_hh  = (const float*)d_in[12];
    const float* gru_b_ih  = (const float*)d_in[13];
    const float* gru_b_hh  = (const float*)d_in[14];
    float* out = (float*)d_out;

    k_setup<<<NE / 256, 256, 0, stream>>>(ei, x, lin0_w, lin0_b, edge_attr,
                                          nn1_w, nn1_b, nn2_w, nn2_b, conv_root,
                                          conv_bias, gru_w_ih, gru_w_hh,
                                          gru_b_ih, gru_b_hh);

    for (int r = 0; r < 6; ++r) {
        k_round<<<NN / NPB, RTHR, 0, stream>>>(out, r & 1, r == 5 ? 1 : 0);
    }
}

// Round 21
// 235.504 us; speedup vs baseline: 2.3515x; 1.0024x over previous
//
#include <hip/hip_runtime.h>

#define NN 12800
#define NE 204800
#define BCAP 64   // bucket capacity per node; P(deg>64) ~ 1e-18
#define NPB 50    // nodes per round-block; 256 blocks x 50 = 12800 = NN
#define RTHR (NPB * 16)  // 800 threads per round-block -> 1 block per CU

// packed-weight layout (floats) -- shared by g_wpack and s_pack
#define OFF_W2 0        // [j*276 + kp*16 + d], bias at [j*276+256+kp]  (4416)
#define OFF_CR 4416     // [k*20+d] = cr[d*16+k]                        (320)
#define OFF_WI 4736     // [row*20+d]                                   (960)
#define OFF_WH 5696     // [row*20+d]                                   (960)
#define OFF_CB 6656     // (16)
#define OFF_BI 6672     // (48)
#define OFF_BH 6720     // (48)
#define PACKN  6768     // total floats (27072 B)

// ---------------- static device scratch (~57 MB) ----------------
__device__ __align__(16) float g_outA[NN * 16];        // node features ping
__device__ __align__(16) float g_outB[NN * 16];        // node features pong
__device__ __align__(16) float g_ehsB[NN * BCAP * 16]; // eh buckets, dst-grouped
__device__ __align__(16) int g_srcB[NN * BCAP];        // src per bucket slot
__device__ int g_cnt[NN];                              // in-degree / cursor (reset by last round)
__device__ int g_perm[NN];                             // degree-balanced node assignment
__device__ __align__(16) float g_wpack[PACKN];         // pre-transposed weights

// ---- S0: lin0 + eh/bucket scatter (edge-parallel); block 0 builds wpack ----
__global__ __launch_bounds__(256) void k_setup(const int* __restrict__ ei,
                                               const float* __restrict__ x,
                                               const float* __restrict__ lw,
                                               const float* __restrict__ lb,
                                               const float* __restrict__ attr,
                                               const float* __restrict__ w1,
                                               const float* __restrict__ b1,
                                               const float* __restrict__ nn2_w,
                                               const float* __restrict__ nn2_b,
                                               const float* __restrict__ cr,
                                               const float* __restrict__ cb,
                                               const float* __restrict__ wi,
                                               const float* __restrict__ wh,
                                               const float* __restrict__ bi,
                                               const float* __restrict__ bh) {
    int gid = blockIdx.x * 256 + threadIdx.x;

    if (blockIdx.x == 0) {
        int tt = threadIdx.x;
        for (int i = tt; i < 4096; i += 256)
            g_wpack[OFF_W2 + (i & 15) * 276 + ((i >> 4) & 15) * 16 + (i >> 8)] = nn2_w[i];
        g_wpack[OFF_W2 + (tt >> 4) * 276 + 256 + (tt & 15)] = nn2_b[tt];
        g_wpack[OFF_CR + (tt & 15) * 20 + (tt >> 4)] = cr[tt];
        for (int i = tt; i < 768; i += 256) {
            g_wpack[OFF_WI + (i >> 4) * 20 + (i & 15)] = wi[i];
            g_wpack[OFF_WH + (i >> 4) * 20 + (i & 15)] = wh[i];
        }
        if (tt < 16) g_wpack[OFF_CB + tt] = cb[tt];
        if (tt < 48) { g_wpack[OFF_BI + tt] = bi[tt]; g_wpack[OFF_BH + tt] = bh[tt]; }
    }

    if (gid < NN) {
        int n = gid;
        float x0 = x[n * 3 + 0], x1 = x[n * 3 + 1], x2 = x[n * 3 + 2];
        float v[16];
#pragma unroll
        for (int j = 0; j < 16; ++j) {
            float t = lb[j] + x0 * lw[j * 3 + 0] + x1 * lw[j * 3 + 1] + x2 * lw[j * 3 + 2];
            v[j] = fmaxf(t, 0.0f);
        }
#pragma unroll
        for (int j = 0; j < 16; j += 4)
            *(float4*)(g_outA + n * 16 + j) = make_float4(v[j], v[j + 1], v[j + 2], v[j + 3]);
    }

    int e = gid;
    int s = ei[e], d = ei[NE + e];
    float4 a = *(const float4*)(attr + e * 4);
    float v[16];
#pragma unroll
    for (int j = 0; j < 16; ++j) {
        float t = b1[j] + a.x * w1[j * 4 + 0] + a.y * w1[j * 4 + 1] +
                  a.z * w1[j * 4 + 2] + a.w * w1[j * 4 + 3];
        v[j] = fmaxf(t, 0.0f);
    }
    int pos = atomicAdd(&g_cnt[d], 1);
    if (pos < BCAP) {
        int slot = d * BCAP + pos;
        g_srcB[slot] = s;
#pragma unroll
        for (int j = 0; j < 16; j += 4)
            *(float4*)(g_ehsB + slot * 16 + j) = make_float4(v[j], v[j + 1], v[j + 2], v[j + 3]);
    }
}

// ---- S1: degree-balanced permutation (counting sort by degree, 1 block) ----
// sorted idx s -> chunk c=s>>2 (4 consecutive-degree nodes form one wave's
// groups), block = c%256 (strided: per-block degree totals equalize).
__global__ __launch_bounds__(1024) void k_perm() {
    __shared__ int hist[64];
    int t = threadIdx.x;
    if (t < 64) hist[t] = 0;
    __syncthreads();
    for (int n = t; n < NN; n += 1024)
        atomicAdd(&hist[min(g_cnt[n], 63)], 1);
    __syncthreads();
    if (t < 64) {
        int v = hist[t];
        int incl = v;
#pragma unroll
        for (int off = 1; off < 64; off <<= 1) {
            int u = __shfl_up(incl, off, 64);
            if (t >= off) incl += u;
        }
        hist[t] = incl - v;                      // exclusive base -> cursor
    }
    __syncthreads();
    for (int n = t; n < NN; n += 1024) {
        int s = atomicAdd(&hist[min(g_cnt[n], 63)], 1);
        int blk, grp;
        if (s < 12288) {                         // 48 full-wave groups per block
            int c = s >> 2, r = s & 3;
            blk = c & 255;
            grp = ((c >> 8) << 2) + r;           // grp 0..47 (12 full waves)
        } else {                                 // top 512 nodes -> half-wave grps
            int l = s - 12288;
            blk = l & 255;
            grp = 48 + (l >> 8);                 // grp 48..49
        }
        g_perm[blk * NPB + grp] = n;
    }
}

// ---- one round. 256 blocks x 800 thr = 50 nodes x 16 lanes; 1 block/CU. ----
__global__ __launch_bounds__(RTHR) void k_round(float* __restrict__ out_final,
                                                int flip, int last) {
    __shared__ __align__(16) float s_pack[PACKN];
    int t = threadIdx.x;
    {   // straight coalesced float4 copy of the pre-transposed pack
        const float4* srcp = (const float4*)g_wpack;
        float4* dstp = (float4*)s_pack;
        for (int idx = t; idx < PACKN / 4; idx += RTHR) dstp[idx] = srcp[idx];
    }
    __syncthreads();

    const float* s_W2  = s_pack + OFF_W2;
    const float* s_crT = s_pack + OFF_CR;
    const float* s_wi  = s_pack + OFF_WI;
    const float* s_wh  = s_pack + OFF_WH;
    const float* s_cb  = s_pack + OFF_CB;
    const float* s_bi  = s_pack + OFF_BI;
    const float* s_bh  = s_pack + OFF_BH;

    const float* cur = flip ? g_outB : g_outA;
    float*       nxt = flip ? g_outA : g_outB;

    const int grp = t >> 4, j = t & 15;          // lane j inside group (grp < 50)
    const int n = min(max(g_perm[blockIdx.x * NPB + grp], 0), NN - 1);
    int deg = min(g_cnt[n], BCAP);               // clamp guards replay corruption
    if (last && j == 0) g_cnt[n] = 0;            // reset for next call's k_setup
    const int base = n * BCAP;

    // ---- G-row accumulation (registers, zero LDS) ----
    float Gd[16];
#pragma unroll
    for (int d = 0; d < 16; ++d) Gd[d] = 0.0f;
    float r16 = 0.0f;
#pragma unroll 4
    for (int q = 0; q < deg; ++q) {
        int slot = base + q;
        int s = min(g_srcB[slot], NN - 1);       // group-uniform
        const float* orow = cur + s * 16;
        float ej = g_ehsB[slot * 16 + j];        // coalesced 64B per group
        float4 o0 = *(const float4*)(orow + 0);  // broadcast
        float4 o1 = *(const float4*)(orow + 4);
        float4 o2 = *(const float4*)(orow + 8);
        float4 o3 = *(const float4*)(orow + 12);
        Gd[0]  += ej * o0.x; Gd[1]  += ej * o0.y; Gd[2]  += ej * o0.z; Gd[3]  += ej * o0.w;
        Gd[4]  += ej * o1.x; Gd[5]  += ej * o1.y; Gd[6]  += ej * o1.z; Gd[7]  += ej * o1.w;
        Gd[8]  += ej * o2.x; Gd[9]  += ej * o2.y; Gd[10] += ej * o2.z; Gd[11] += ej * o2.w;
        Gd[12] += ej * o3.x; Gd[13] += ej * o3.y; Gd[14] += ej * o3.z; Gd[15] += ej * o3.w;
        r16 += orow[j];
    }

    // ---- contraction: part[k'] via b128 s_W2 reads ----
    const float* wj = s_W2 + j * 276;
    float part[16];
#pragma unroll
    for (int kp = 0; kp < 16; ++kp) {
        const float* w = wj + kp * 16;
        float4 w0 = *(const float4*)(w + 0);
        float4 w1 = *(const float4*)(w + 4);
        float4 w2 = *(const float4*)(w + 8);
        float4 w3 = *(const float4*)(w + 12);
        part[kp] = Gd[0] * w0.x + Gd[1] * w0.y + Gd[2] * w0.z + Gd[3] * w0.w
                 + Gd[4] * w1.x + Gd[5] * w1.y + Gd[6] * w1.z + Gd[7] * w1.w
                 + Gd[8] * w2.x + Gd[9] * w2.y + Gd[10] * w2.z + Gd[11] * w2.w
                 + Gd[12] * w3.x + Gd[13] * w3.y + Gd[14] * w3.z + Gd[15] * w3.w;
    }
    {   // fold bias row: part[k'] += r16 * b2[j*16+k']
        float4 b0 = *(const float4*)(wj + 256);
        float4 b1 = *(const float4*)(wj + 260);
        float4 b2v = *(const float4*)(wj + 264);
        float4 b3 = *(const float4*)(wj + 268);
        part[0] += r16 * b0.x;  part[1] += r16 * b0.y;  part[2] += r16 * b0.z;  part[3] += r16 * b0.w;
        part[4] += r16 * b1.x;  part[5] += r16 * b1.y;  part[6] += r16 * b1.z;  part[7] += r16 * b1.w;
        part[8] += r16 * b2v.x; part[9] += r16 * b2v.y; part[10] += r16 * b2v.z; part[11] += r16 * b2v.w;
        part[12] += r16 * b3.x; part[13] += r16 * b3.y; part[14] += r16 * b3.z; part[15] += r16 * b3.w;
    }

    // ---- j-reduction: halving butterfly, 15 shfl_xor; lane j ends with a[j] --
    float w8[8];
#pragma unroll
    for (int i = 0; i < 8; ++i) {
        int keep = 2 * i + (j & 1);
        w8[i] = part[keep] + __shfl_xor(part[keep ^ 1], 1);
    }
    float w4[4];
#pragma unroll
    for (int i = 0; i < 4; ++i) {
        int keep = 2 * i + ((j >> 1) & 1);
        w4[i] = w8[keep] + __shfl_xor(w8[keep ^ 1], 2);
    }
    float w2[2];
#pragma unroll
    for (int i = 0; i < 2; ++i) {
        int keep = 2 * i + ((j >> 2) & 1);
        w2[i] = w4[keep] + __shfl_xor(w4[keep ^ 1], 4);
    }
    float aggr;
    {
        int keep = (j >> 3) & 1;
        aggr = w2[keep] + __shfl_xor(w2[keep ^ 1], 8);
    }
    float invd = 1.0f / (float)(deg > 0 ? deg : 1);
    float a_k = aggr * invd;
    const int k = j;

    // ---- node update: conv + GRU (b128 LDS weights) ----
    const float* nrow = cur + n * 16;
    float4 q0 = *(const float4*)(nrow + 0);
    float4 q1 = *(const float4*)(nrow + 4);
    float4 q2 = *(const float4*)(nrow + 8);
    float4 q3 = *(const float4*)(nrow + 12);
    float o[16] = {q0.x, q0.y, q0.z, q0.w, q1.x, q1.y, q1.z, q1.w,
                   q2.x, q2.y, q2.z, q2.w, q3.x, q3.y, q3.z, q3.w};
    float ok = o[k];

    float mcc = s_cb[k] + a_k;
    {
        const float* c = s_crT + k * 20;
        float4 c0 = *(const float4*)(c + 0);
        float4 c1 = *(const float4*)(c + 4);
        float4 c2 = *(const float4*)(c + 8);
        float4 c3 = *(const float4*)(c + 12);
        mcc += o[0] * c0.x + o[1] * c0.y + o[2] * c0.z + o[3] * c0.w
             + o[4] * c1.x + o[5] * c1.y + o[6] * c1.z + o[7] * c1.w
             + o[8] * c2.x + o[9] * c2.y + o[10] * c2.z + o[11] * c2.w
             + o[12] * c3.x + o[13] * c3.y + o[14] * c3.z + o[15] * c3.w;
    }
    float m = fmaxf(mcc, 0.0f);

    float md[16];
#pragma unroll
    for (int d = 0; d < 16; ++d) md[d] = __shfl(m, d, 16);

    float ir = s_bi[k], iz = s_bi[16 + k], in_ = s_bi[32 + k];
    float hr = s_bh[k], hz = s_bh[16 + k], hh = s_bh[32 + k];
#pragma unroll
    for (int g = 0; g < 3; ++g) {
        const float* wrow_i = s_wi + (g * 16 + k) * 20;
        const float* wrow_h = s_wh + (g * 16 + k) * 20;
        float acc_i = 0.0f, acc_h = 0.0f;
#pragma unroll
        for (int d4 = 0; d4 < 4; ++d4) {
            float4 wiv = *(const float4*)(wrow_i + d4 * 4);
            float4 whv = *(const float4*)(wrow_h + d4 * 4);
            acc_i += md[d4 * 4] * wiv.x + md[d4 * 4 + 1] * wiv.y
                   + md[d4 * 4 + 2] * wiv.z + md[d4 * 4 + 3] * wiv.w;
            acc_h += o[d4 * 4] * whv.x + o[d4 * 4 + 1] * whv.y
                   + o[d4 * 4 + 2] * whv.z + o[d4 * 4 + 3] * whv.w;
        }
        if (g == 0) { ir += acc_i; hr += acc_h; }
        else if (g == 1) { iz += acc_i; hz += acc_h; }
        else { in_ += acc_i; hh += acc_h; }
    }
    float rg = 1.0f / (1.0f + __expf(-(ir + hr)));
    float z  = 1.0f / (1.0f + __expf(-(iz + hz)));
    float nh = tanhf(in_ + rg * hh);
    float hnew = (1.0f - z) * nh + z * ok;

    if (last) out_final[n * 16 + k] = hnew;
    else      nxt[n * 16 + k] = hnew;
}

extern "C" void kernel_launch(void* const* d_in, const int* in_sizes, int n_in,
                              void* d_out, int out_size, void* d_ws, size_t ws_size,
                              hipStream_t stream) {
    const float* x         = (const float*)d_in[0];
    const int*   ei        = (const int*)d_in[1];
    const float* edge_attr = (const float*)d_in[2];
    const float* lin0_w    = (const float*)d_in[3];
    const float* lin0_b    = (const float*)d_in[4];
    const float* nn1_w     = (const float*)d_in[5];
    const float* nn1_b     = (const float*)d_in[6];
    const float* nn2_w     = (const float*)d_in[7];
    const float* nn2_b     = (const float*)d_in[8];
    const float* conv_root = (const float*)d_in[9];
    const float* conv_bias = (const float*)d_in[10];
    const float* gru_w_ih  = (const float*)d_in[11];
    const float* gru_w_hh  = (const float*)d_in[12];
    const float* gru_b_ih  = (const float*)d_in[13];
    const float* gru_b_hh  = (const float*)d_in[14];
    float* out = (float*)d_out;

    k_setup<<<NE / 256, 256, 0, stream>>>(ei, x, lin0_w, lin0_b, edge_attr,
                                          nn1_w, nn1_b, nn2_w, nn2_b, conv_root,
                                          conv_bias, gru_w_ih, gru_w_hh,
                                          gru_b_ih, gru_b_hh);
    k_perm<<<1, 1024, 0, stream>>>();

    for (int r = 0; r < 6; ++r) {
        k_round<<<NN / NPB, RTHR, 0, stream>>>(out, r & 1, r == 5 ? 1 : 0);
    }
}